// Round 1
// baseline (700.578 us; speedup 1.0000x reference)
//
#include <hip/hip_runtime.h>

typedef float  f32x4  __attribute__((ext_vector_type(4)));
typedef __bf16 bf16x8 __attribute__((ext_vector_type(8)));
typedef short  s16x8  __attribute__((ext_vector_type(8)));
typedef short  s16x4  __attribute__((ext_vector_type(4)));

// fp32 -> bf16 round-to-nearest-even (raw bits in short)
__device__ __forceinline__ short f2b(float f) {
  unsigned u = __builtin_bit_cast(unsigned, f);
  u = (u + 0x7fffu + ((u >> 16) & 1u)) >> 16;
  return (short)u;
}
// bf16 bits -> fp32 (exact)
__device__ __forceinline__ float b2f(short s) {
  unsigned u = ((unsigned)(unsigned short)s) << 16;
  return __builtin_bit_cast(float, u);
}

// W [2][256 c][256 d] fp32  ->  Wt [2][256 d][256 c] bf16 (B-operand friendly)
__global__ void prep_wt(const float* __restrict__ W, short* __restrict__ Wt) {
  int q = blockIdx.x * blockDim.x + threadIdx.x;   // 0..32767, each handles 4 elems
  int mat = q >> 14;
  int rem = q & 16383;
  int d   = rem >> 6;
  int c4  = (rem & 63) << 2;
  const float* src = W + mat * 65536;
  s16x4 o;
  #pragma unroll
  for (int i = 0; i < 4; ++i) o[i] = f2b(src[(c4 + i) * 256 + d]);
  *(s16x4*)&Wt[q << 2] = o;   // flat = mat*65536 + d*256 + c4
}

// Fused: h0=x@W0, h1=x@W1 (bf16 MFMA), then
// out[b,i,d] = diag_i*M[i,d]*h0[b,i,d] + sum_{j!=i} Asym[i,j]*M[j,d]*h1[b,j,d] + bias[d]
// Block: 8 batches (136 rows, padded to 144) x 128 d-cols. 4 waves; wave w owns cols [w*32,w*32+32).
__global__ __launch_bounds__(256, 2)
void fused_mgc(const float* __restrict__ x, const short* __restrict__ Wt,
               const float* __restrict__ M, const float* __restrict__ adj,
               const float* __restrict__ adj2, const float* __restrict__ bias,
               float* __restrict__ out) {
  __shared__ short smem[28800];   // union: K-loop staging (57.6KB) / epilogue s,g bufs (35.9KB)
  __shared__ float aoff[289];     // symmetrized A, diagonal zeroed
  __shared__ float diagl[17];     // diag of A (= adj[ii]+adj2[ii])

  const int tid  = threadIdx.x;
  const int lane = tid & 63;
  const int wv   = tid >> 6;
  const int m16  = lane & 15;
  const int qd   = lane >> 4;

  const int bt = blockIdx.x >> 1;  // batch tile (8 batches): rows bt*136..+136 (136 = 8*17, so n = r%17)
  const int ct = blockIdx.x & 1;   // col tile (128 d); ct fast => L3 reuse of x across the 2 col-tiles

  for (int idx = tid; idx < 289; idx += 256) {
    int i = idx / 17, j = idx - i * 17;
    float v = 0.5f * ((adj[i*17+j] + adj2[i*17+j]) + (adj[j*17+i] + adj2[j*17+i]));
    aoff[idx] = (i == j) ? 0.0f : v;
    if (i == j) diagl[i] = adj[i*17+i] + adj2[i*17+i];
  }

  f32x4 acc[9][4];  // [rowfrag][mat*2+colfrag]
  #pragma unroll
  for (int a = 0; a < 9; ++a)
    #pragma unroll
    for (int b = 0; b < 4; ++b) acc[a][b] = (f32x4)0.0f;

  short* xs  = smem;           // [144][72] bf16  (stride 72: 16B-aligned, 2-way banks = free)
  short* wsm = smem + 10368;   // [2][128][72] bf16

  const int xrow = tid >> 4;         // 0..15
  const int xc4  = (tid & 15) << 2;  // 0..60
  const int wcol = tid >> 3;         // 0..31
  const int wk8  = (tid & 7) << 3;   // 0..56

  for (int kc = 0; kc < 4; ++kc) {   // K chunks of 64
    __syncthreads();
    #pragma unroll
    for (int p = 0; p < 9; ++p) {    // x: 144 rows x 64 k, fp32->bf16
      int row = p * 16 + xrow;
      s16x4 v; v[0] = 0; v[1] = 0; v[2] = 0; v[3] = 0;
      if (row < 136) {
        const f32x4 xv = *(const f32x4*)&x[(bt*136 + row)*256 + kc*64 + xc4];
        v[0] = f2b(xv[0]); v[1] = f2b(xv[1]); v[2] = f2b(xv[2]); v[3] = f2b(xv[3]);
      }
      *(s16x4*)&xs[row*72 + xc4] = v;
    }
    #pragma unroll
    for (int mp = 0; mp < 8; ++mp) { // Wt tiles: 2 mats x 128 cols x 64 k (bf16 already)
      int mat = mp >> 2;
      int col = (mp & 3) * 32 + wcol;
      s16x8 wvv = *(const s16x8*)&Wt[mat*65536 + (ct*128 + col)*256 + kc*64 + wk8];
      *(s16x8*)&wsm[mat*9216 + col*72 + wk8] = wvv;
    }
    __syncthreads();
    #pragma unroll
    for (int ks = 0; ks < 2; ++ks) {
      const int kq = ks*32 + qd*8;   // A/B operand: k = (lane>>4)*8 + elem
      bf16x8 bf[4];
      #pragma unroll
      for (int mc = 0; mc < 4; ++mc) {
        int mat = mc >> 1, cf = mc & 1;
        s16x8 t = *(const s16x8*)&wsm[mat*9216 + (wv*32 + cf*16 + m16)*72 + kq];
        bf[mc] = __builtin_bit_cast(bf16x8, t);
      }
      #pragma unroll
      for (int rf = 0; rf < 9; ++rf) {
        s16x8 t = *(const s16x8*)&xs[(rf*16 + m16)*72 + kq];
        bf16x8 af = __builtin_bit_cast(bf16x8, t);
        #pragma unroll
        for (int mc = 0; mc < 4; ++mc)
          acc[rf][mc] = __builtin_amdgcn_mfma_f32_16x16x32_bf16(af, bf[mc], acc[rf][mc], 0, 0, 0);
      }
    }
  }

  // ---- epilogue: two passes of 68 rows (4 batch-groups each) to keep LDS < 64KB ----
  short* sbuf = smem;          // [68][132] bf16: diag_i*M*h0
  short* gbuf = smem + 8976;   // [68][132] bf16: M*h1
  const int d7   = tid & 127;
  const int half = tid >> 7;
  const float bi = bias[ct*128 + d7];

  #pragma unroll
  for (int pass = 0; pass < 2; ++pass) {
    __syncthreads();
    // phase 1: registers (C-layout: col=lane&15, row=(lane>>4)*4+reg) -> LDS
    #pragma unroll
    for (int rf = 0; rf < 9; ++rf) {
      #pragma unroll
      for (int cf = 0; cf < 2; ++cf) {
        int c = wv*32 + cf*16 + m16;
        #pragma unroll
        for (int reg = 0; reg < 4; ++reg) {
          int r  = rf*16 + qd*4 + reg;
          int rl = r - pass*68;
          if (rl >= 0 && rl < 68) {           // pad rows 136..143 excluded automatically
            int n = r % 17;
            float mv = M[n*256 + ct*128 + c];
            sbuf[rl*132 + c] = f2b(diagl[n] * mv * acc[rf][cf][reg]);
            gbuf[rl*132 + c] = f2b(mv * acc[rf][2+cf][reg]);
          }
        }
      }
    }
    __syncthreads();
    // phase 2: mixing. i,j uniform across threads -> aoff reads are broadcasts.
    for (int gg = 0; gg < 2; ++gg) {
      int g = pass*4 + half*2 + gg;          // batch-group within tile
      int rbase = g*17 - pass*68;
      float gr[17];
      #pragma unroll
      for (int j = 0; j < 17; ++j) gr[j] = b2f(gbuf[(rbase + j)*132 + d7]);
      #pragma unroll
      for (int i = 0; i < 17; ++i) {
        float s = b2f(sbuf[(rbase + i)*132 + d7]) + bi;
        #pragma unroll
        for (int j = 0; j < 17; ++j) s += aoff[i*17 + j] * gr[j];
        out[((bt*8 + g)*17 + i)*256 + ct*128 + d7] = s;
      }
    }
  }
}

extern "C" void kernel_launch(void* const* d_in, const int* in_sizes, int n_in,
                              void* d_out, int out_size, void* d_ws, size_t ws_size,
                              hipStream_t stream) {
  const float* x    = (const float*)d_in[0];
  const float* W    = (const float*)d_in[1];
  const float* M    = (const float*)d_in[2];
  const float* adj  = (const float*)d_in[3];
  const float* adj2 = (const float*)d_in[4];
  const float* bias = (const float*)d_in[5];
  float* out = (float*)d_out;
  short* Wt  = (short*)d_ws;   // 262144 B scratch for transposed bf16 weights

  prep_wt<<<128, 256, 0, stream>>>(W, Wt);
  fused_mgc<<<2048, 256, 0, stream>>>(x, Wt, M, adj, adj2, bias, out);
}

// Round 2
// 507.521 us; speedup vs baseline: 1.3804x; 1.3804x over previous
//
#include <hip/hip_runtime.h>

typedef float  f32x4  __attribute__((ext_vector_type(4)));
typedef __bf16 bf16x8 __attribute__((ext_vector_type(8)));
typedef short  s16x8  __attribute__((ext_vector_type(8)));
typedef short  s16x4  __attribute__((ext_vector_type(4)));

// fp32 -> bf16 round-to-nearest-even (raw bits in short)
__device__ __forceinline__ short f2b(float f) {
  unsigned u = __builtin_bit_cast(unsigned, f);
  u = (u + 0x7fffu + ((u >> 16) & 1u)) >> 16;
  return (short)u;
}
// bf16 bits -> fp32 (exact)
__device__ __forceinline__ float b2f(short s) {
  unsigned u = ((unsigned)(unsigned short)s) << 16;
  return __builtin_bit_cast(float, u);
}

// W [2][256 c][256 d] fp32  ->  Wt [2][256 d][256 c] bf16 (B-operand friendly)
__global__ void prep_wt(const float* __restrict__ W, short* __restrict__ Wt) {
  int q = blockIdx.x * blockDim.x + threadIdx.x;   // 0..32767, each handles 4 elems
  int mat = q >> 14;
  int rem = q & 16383;
  int d   = rem >> 6;
  int c4  = (rem & 63) << 2;
  const float* src = W + mat * 65536;
  s16x4 o;
  #pragma unroll
  for (int i = 0; i < 4; ++i) o[i] = f2b(src[(c4 + i) * 256 + d]);
  *(s16x4*)&Wt[q << 2] = o;   // flat = mat*65536 + d*256 + c4
}

// Fused: h0=x@W0, h1=x@W1 (bf16 MFMA), then
// out[b,i,d] = diag_i*M[i,d]*h0[b,i,d] + sum_{j!=i} Asym[i,j]*M[j,d]*h1[b,j,d] + bias[d]
// Block: 8 batches (136 rows, padded to 144) x 128 d-cols. 4 waves; wave w owns cols [w*32,w*32+32).
// launch_bounds(256,1): acc[9][4] f32x4 = 144 VGPR + operands ~190 total. The
// (256,2)=128-VGPR cap forced accumulator spill to scratch (WRITE_SIZE 1.13GB vs
// 143MB ideal, 547us). At ~200 VGPR we still get 2 waves/SIMD = 2 blocks/CU,
// which the 58.8KB LDS already caps us at — occupancy unchanged, spill deleted.
__global__ __launch_bounds__(256, 1)
void fused_mgc(const float* __restrict__ x, const short* __restrict__ Wt,
               const float* __restrict__ M, const float* __restrict__ adj,
               const float* __restrict__ adj2, const float* __restrict__ bias,
               float* __restrict__ out) {
  __shared__ short smem[28800];   // union: K-loop staging (57.6KB) / epilogue s,g bufs (35.9KB)
  __shared__ float aoff[289];     // symmetrized A, diagonal zeroed
  __shared__ float diagl[17];     // diag of A (= adj[ii]+adj2[ii])

  const int tid  = threadIdx.x;
  const int lane = tid & 63;
  const int wv   = tid >> 6;
  const int m16  = lane & 15;
  const int qd   = lane >> 4;

  const int bt = blockIdx.x >> 1;  // batch tile (8 batches): rows bt*136..+136 (136 = 8*17, so n = r%17)
  const int ct = blockIdx.x & 1;   // col tile (128 d); ct fast => L3 reuse of x across the 2 col-tiles

  for (int idx = tid; idx < 289; idx += 256) {
    int i = idx / 17, j = idx - i * 17;
    float v = 0.5f * ((adj[i*17+j] + adj2[i*17+j]) + (adj[j*17+i] + adj2[j*17+i]));
    aoff[idx] = (i == j) ? 0.0f : v;
    if (i == j) diagl[i] = adj[i*17+i] + adj2[i*17+i];
  }

  f32x4 acc[9][4];  // [rowfrag][mat*2+colfrag]
  #pragma unroll
  for (int a = 0; a < 9; ++a)
    #pragma unroll
    for (int b = 0; b < 4; ++b) acc[a][b] = (f32x4)0.0f;

  short* xs  = smem;           // [144][72] bf16  (stride 72: 16B-aligned, 2-way banks = free)
  short* wsm = smem + 10368;   // [2][128][72] bf16

  const int xrow = tid >> 4;         // 0..15
  const int xc4  = (tid & 15) << 2;  // 0..60
  const int wcol = tid >> 3;         // 0..31
  const int wk8  = (tid & 7) << 3;   // 0..56

  for (int kc = 0; kc < 4; ++kc) {   // K chunks of 64
    __syncthreads();
    #pragma unroll
    for (int p = 0; p < 9; ++p) {    // x: 144 rows x 64 k, fp32->bf16
      int row = p * 16 + xrow;
      s16x4 v; v[0] = 0; v[1] = 0; v[2] = 0; v[3] = 0;
      if (row < 136) {
        const f32x4 xv = *(const f32x4*)&x[(bt*136 + row)*256 + kc*64 + xc4];
        v[0] = f2b(xv[0]); v[1] = f2b(xv[1]); v[2] = f2b(xv[2]); v[3] = f2b(xv[3]);
      }
      *(s16x4*)&xs[row*72 + xc4] = v;
    }
    #pragma unroll
    for (int mp = 0; mp < 8; ++mp) { // Wt tiles: 2 mats x 128 cols x 64 k (bf16 already)
      int mat = mp >> 2;
      int col = (mp & 3) * 32 + wcol;
      s16x8 wvv = *(const s16x8*)&Wt[mat*65536 + (ct*128 + col)*256 + kc*64 + wk8];
      *(s16x8*)&wsm[mat*9216 + col*72 + wk8] = wvv;
    }
    __syncthreads();
    #pragma unroll
    for (int ks = 0; ks < 2; ++ks) {
      const int kq = ks*32 + qd*8;   // A/B operand: k = (lane>>4)*8 + elem
      bf16x8 bf[4];
      #pragma unroll
      for (int mc = 0; mc < 4; ++mc) {
        int mat = mc >> 1, cf = mc & 1;
        s16x8 t = *(const s16x8*)&wsm[mat*9216 + (wv*32 + cf*16 + m16)*72 + kq];
        bf[mc] = __builtin_bit_cast(bf16x8, t);
      }
      #pragma unroll
      for (int rf = 0; rf < 9; ++rf) {
        s16x8 t = *(const s16x8*)&xs[(rf*16 + m16)*72 + kq];
        bf16x8 af = __builtin_bit_cast(bf16x8, t);
        #pragma unroll
        for (int mc = 0; mc < 4; ++mc)
          acc[rf][mc] = __builtin_amdgcn_mfma_f32_16x16x32_bf16(af, bf[mc], acc[rf][mc], 0, 0, 0);
      }
    }
  }

  // ---- epilogue: two passes of 68 rows (4 batch-groups each) to keep LDS < 64KB ----
  short* sbuf = smem;          // [68][132] bf16: diag_i*M*h0
  short* gbuf = smem + 8976;   // [68][132] bf16: M*h1
  const int d7   = tid & 127;
  const int half = tid >> 7;
  const float bi = bias[ct*128 + d7];

  #pragma unroll
  for (int pass = 0; pass < 2; ++pass) {
    __syncthreads();
    // phase 1: registers (C-layout: col=lane&15, row=(lane>>4)*4+reg) -> LDS
    #pragma unroll
    for (int rf = 0; rf < 9; ++rf) {
      #pragma unroll
      for (int cf = 0; cf < 2; ++cf) {
        int c = wv*32 + cf*16 + m16;
        #pragma unroll
        for (int reg = 0; reg < 4; ++reg) {
          int r  = rf*16 + qd*4 + reg;
          int rl = r - pass*68;
          if (rl >= 0 && rl < 68) {           // pad rows 136..143 excluded automatically
            int n = r % 17;
            float mv = M[n*256 + ct*128 + c];
            sbuf[rl*132 + c] = f2b(diagl[n] * mv * acc[rf][cf][reg]);
            gbuf[rl*132 + c] = f2b(mv * acc[rf][2+cf][reg]);
          }
        }
      }
    }
    __syncthreads();
    // phase 2: mixing. i,j uniform across threads -> aoff reads are broadcasts.
    for (int gg = 0; gg < 2; ++gg) {
      int g = pass*4 + half*2 + gg;          // batch-group within tile
      int rbase = g*17 - pass*68;
      float gr[17];
      #pragma unroll
      for (int j = 0; j < 17; ++j) gr[j] = b2f(gbuf[(rbase + j)*132 + d7]);
      #pragma unroll
      for (int i = 0; i < 17; ++i) {
        float s = b2f(sbuf[(rbase + i)*132 + d7]) + bi;
        #pragma unroll
        for (int j = 0; j < 17; ++j) s += aoff[i*17 + j] * gr[j];
        out[((bt*8 + g)*17 + i)*256 + ct*128 + d7] = s;
      }
    }
  }
}

extern "C" void kernel_launch(void* const* d_in, const int* in_sizes, int n_in,
                              void* d_out, int out_size, void* d_ws, size_t ws_size,
                              hipStream_t stream) {
  const float* x    = (const float*)d_in[0];
  const float* W    = (const float*)d_in[1];
  const float* M    = (const float*)d_in[2];
  const float* adj  = (const float*)d_in[3];
  const float* adj2 = (const float*)d_in[4];
  const float* bias = (const float*)d_in[5];
  float* out = (float*)d_out;
  short* Wt  = (short*)d_ws;   // 262144 B scratch for transposed bf16 weights

  prep_wt<<<128, 256, 0, stream>>>(W, Wt);
  fused_mgc<<<2048, 256, 0, stream>>>(x, Wt, M, adj, adj2, bias, out);
}